// Round 16
// baseline (329.071 us; speedup 1.0000x reference)
//
#include <hip/hip_runtime.h>
#include <stdint.h>

#define B_DIM 8192
#define K_DIM 2048
#define N_DIM 2048
#define NSEG 4
#define NT (K_DIM / 64)   // 32 K-tiles of BK=64

typedef int v4i __attribute__((ext_vector_type(4)));

typedef const __attribute__((address_space(1))) void* gas_ptr;
typedef __attribute__((address_space(3))) void* lds_ptr;

// ---- fused: x row quantize (per-row int8) + gates = sigmoid(x@Wg^T+bg) ----
__global__ __launch_bounds__(256)
void xquant_gates_kernel(const float* __restrict__ x, const float* __restrict__ Wg,
                         const float* __restrict__ bg, signed char* __restrict__ xq,
                         float* __restrict__ sx, float* __restrict__ gates) {
  const int b = blockIdx.x;
  const int tid = threadIdx.x;
  const size_t base = (size_t)b * K_DIM + tid * 8;
  const float4 v0 = *(const float4*)(x + base);
  const float4 v1 = *(const float4*)(x + base + 4);

  float a[4];
#pragma unroll
  for (int s = 0; s < 4; ++s) {
    const float4 w0 = *(const float4*)(Wg + (size_t)s * K_DIM + tid * 8);
    const float4 w1 = *(const float4*)(Wg + (size_t)s * K_DIM + tid * 8 + 4);
    a[s] = v0.x * w0.x + v0.y * w0.y + v0.z * w0.z + v0.w * w0.w
         + v1.x * w1.x + v1.y * w1.y + v1.z * w1.z + v1.w * w1.w;
  }
  float m = fmaxf(fmaxf(fmaxf(fabsf(v0.x), fabsf(v0.y)), fmaxf(fabsf(v0.z), fabsf(v0.w))),
                  fmaxf(fmaxf(fabsf(v1.x), fabsf(v1.y)), fmaxf(fabsf(v1.z), fabsf(v1.w))));
#pragma unroll
  for (int off = 1; off < 64; off <<= 1) {
    m = fmaxf(m, __shfl_xor(m, off));
#pragma unroll
    for (int s = 0; s < 4; ++s) a[s] += __shfl_xor(a[s], off);
  }
  __shared__ float redg[4][4];
  __shared__ float rmx[4];
  const int wv = tid >> 6;
  if ((tid & 63) == 0) {
    rmx[wv] = m;
#pragma unroll
    for (int s = 0; s < 4; ++s) redg[wv][s] = a[s];
  }
  __syncthreads();
  const float rm = fmaxf(fmaxf(rmx[0], rmx[1]), fmaxf(rmx[2], rmx[3]));
  const float inv = 127.0f / fmaxf(rm, 1e-30f);
  const int q0 = __float2int_rn(v0.x * inv), q1 = __float2int_rn(v0.y * inv);
  const int q2 = __float2int_rn(v0.z * inv), q3 = __float2int_rn(v0.w * inv);
  const int q4 = __float2int_rn(v1.x * inv), q5 = __float2int_rn(v1.y * inv);
  const int q6 = __float2int_rn(v1.z * inv), q7 = __float2int_rn(v1.w * inv);
  const int lo = (q0 & 255) | ((q1 & 255) << 8) | ((q2 & 255) << 16) | ((q3 & 255) << 24);
  const int hi = (q4 & 255) | ((q5 & 255) << 8) | ((q6 & 255) << 16) | ((q7 & 255) << 24);
  ((int2*)xq)[(size_t)b * 256 + tid] = make_int2(lo, hi);
  if (tid == 0) sx[b] = rm * (1.0f / 127.0f);
  if (tid < 4) {
    float v = redg[0][tid] + redg[1][tid] + redg[2][tid] + redg[3][tid] + bg[tid];
    gates[(size_t)b * 4 + tid] = 1.f / (1.f + __expf(-v));
  }
}

// ---- W row quantize: one block per (seg,d) row of 2048 ----
__global__ __launch_bounds__(256)
void wquant_kernel(const float* __restrict__ W, signed char* __restrict__ wq,
                   float* __restrict__ sw) {
  const int row = blockIdx.x;           // s*N_DIM + d
  const int tid = threadIdx.x;
  const size_t base = (size_t)row * K_DIM + tid * 8;
  const float4 v0 = *(const float4*)(W + base);
  const float4 v1 = *(const float4*)(W + base + 4);
  float m = fmaxf(fmaxf(fmaxf(fabsf(v0.x), fabsf(v0.y)), fmaxf(fabsf(v0.z), fabsf(v0.w))),
                  fmaxf(fmaxf(fabsf(v1.x), fabsf(v1.y)), fmaxf(fabsf(v1.z), fabsf(v1.w))));
#pragma unroll
  for (int off = 1; off < 64; off <<= 1) m = fmaxf(m, __shfl_xor(m, off));
  __shared__ float rmx[4];
  if ((tid & 63) == 0) rmx[tid >> 6] = m;
  __syncthreads();
  const float rm = fmaxf(fmaxf(rmx[0], rmx[1]), fmaxf(rmx[2], rmx[3]));
  const float inv = 127.0f / fmaxf(rm, 1e-30f);
  const int q0 = __float2int_rn(v0.x * inv), q1 = __float2int_rn(v0.y * inv);
  const int q2 = __float2int_rn(v0.z * inv), q3 = __float2int_rn(v0.w * inv);
  const int q4 = __float2int_rn(v1.x * inv), q5 = __float2int_rn(v1.y * inv);
  const int q6 = __float2int_rn(v1.z * inv), q7 = __float2int_rn(v1.w * inv);
  const int lo = (q0 & 255) | ((q1 & 255) << 8) | ((q2 & 255) << 16) | ((q3 & 255) << 24);
  const int hi = (q4 & 255) | ((q5 & 255) << 8) | ((q6 & 255) << 16) | ((q7 & 255) << 24);
  ((int2*)wq)[(size_t)row * 256 + tid] = make_int2(lo, hi);
  if (tid == 0) sw[row] = rm * (1.0f / 127.0f);
}

// ---- fused 4-seg GEMM, i8 16x16x64: A direct-to-register, B via LDS --------
// Geometry/grid/mapping = R14 (passed, 184us): block 128 r x 64 d x 4 segs;
// 8 waves 2Mx4N; per-wave 64 r x 16 d x 4 segs; acc v4i[4][4] (AGPR);
// XCD-local 2D window mapping (FETCH 474->112 MB).
// NEW vs R14: A never touches LDS. A-fragments are natural 16B/lane global
// loads (row = m0+wm*64+f*16+l15, k-chunk kg) -- A rows are shared by the 4
// wn-waves and L1/L2-hot under the window mapping. Removes the 4x LDS
// read duplication of A + all A staging writes: LDS work/tile drops from
// {8 reads + 20KB writes} to {4 reads + 12KB writes}.
// Register budget (R15 spill lesson): a[4]=16 + bfr[4]=16 + addr ~20 < 64
// VGPR alongside 64 AGPR acc at launch_bounds(512,4). NO A double-buffer.
// Issue order/tile: a-loads(4) -> B-stage(t+2)(2) -> 4 B ds_reads -> MFMAs.
// Compiler's a[]-dep wait = vmcnt(2): drains a[] AND B(t+1) (older), leaves
// B(t+2) flying with 2-tile cover. Tail = barrier only. B tri-ring 3x16KB =
// 48KB/block -> 2 blocks/CU.
__global__ __launch_bounds__(512, 4)
void seg_gemm_kernel(const signed char* __restrict__ Xq,
                     const signed char* __restrict__ Wq,
                     const float* __restrict__ sx,
                     const float* __restrict__ sw,
                     const float* __restrict__ b_seg,
                     const float* __restrict__ thr,
                     const float* __restrict__ gates,
                     float* __restrict__ out) {
  __shared__ __align__(128) char smem[49152];   // B tri-ring 3 x 16KB

  const int tid = threadIdx.x;
  const int lane = tid & 63;
  const int wid = tid >> 6;
  const int wm = wid >> 2;        // 0..1 (m half: 64 rows)
  const int wn = wid & 3;         // 0..3 (d quarter)

  // ---- XCD-local 2D window mapping (bijective, R14) ----
  const int id = blockIdx.x;
  const int x = id & 7;
  const int c = id >> 3;
  const int mIdx = (c >> 3) & 7;
  const int nIdx = (c & 7) | ((c >> 6) << 3);
  const int m0 = (x * 8 + mIdx) * 128;
  const int n0 = nIdx * 64;

  // ---- B staging constants (verified zero-conflict, R10-R14) ----
  const int kc    = (tid & 3) ^ ((tid >> 3) & 3);    // chunk swizzle (involution)
  const int keOff = kc * 16;
  const int ldsd  = tid * 16;

  // ---- read constants ----
  const int l15 = lane & 15;
  const int kg  = lane >> 4;       // 0..3
  const int aSw = l15 * 64 + ((kg ^ ((l15 >> 1) & 3)) << 4);

  // A direct-load base: lane (l15,kg) reads Xq[m0+wm*64+f*16+l15][t*64+kg*16..]
  const signed char* wA = Xq + (size_t)(m0 + wm * 64 + l15) * K_DIM + kg * 16;
#define AROW ((size_t)16 * K_DIM)

  v4i acc[NSEG][4];
#pragma unroll
  for (int s = 0; s < NSEG; ++s)
#pragma unroll
    for (int f = 0; f < 4; ++f) acc[s][f] = (v4i){0, 0, 0, 0};

#define STAGE_B(t_, h_, bb_) do {                                                   \
    const signed char* s0_ = Wq + ((size_t)((h_) * 2 + (tid >> 8)) * N_DIM + (n0 + ((tid >> 2) & 63))) * K_DIM + (t_) * 64 + keOff; \
    __builtin_amdgcn_global_load_lds((gas_ptr)s0_, (lds_ptr)(smem + (bb_) * 16384 + (h_) * 8192 + ldsd), 16, 0, 0); \
  } while (0)

#define MFMAI(a_, b_, c_) __builtin_amdgcn_mfma_i32_16x16x64_i8(a_, b_, c_, 0, 0, 0)
#define LD16(p_) (*(const v4i*)(p_))
#define WAITL(n_) asm volatile("s_waitcnt lgkmcnt(" #n_ ")" ::: "memory")
#define FENCE asm volatile("" ::: "memory")

#define MM4(f_) do {                                                                \
    acc[0][(f_)] = MFMAI(a[(f_)], bfr[0], acc[0][(f_)]);                            \
    acc[1][(f_)] = MFMAI(a[(f_)], bfr[1], acc[1][(f_)]);                            \
    acc[2][(f_)] = MFMAI(a[(f_)], bfr[2], acc[2][(f_)]);                            \
    acc[3][(f_)] = MFMAI(a[(f_)], bfr[3], acc[3][(f_)]);                            \
  } while (0)

  // ---- prologue: B(0)->slot0, B(1)->slot1; drain B(0), keep B(1) flying ----
  STAGE_B(0, 0, 0); STAGE_B(0, 1, 0);
  STAGE_B(1, 0, 1); STAGE_B(1, 1, 1);
  asm volatile("s_waitcnt vmcnt(2)" ::: "memory");   // B(0) landed
  __builtin_amdgcn_s_barrier();

  int bc = 0, bs = 2;   // current / stage-target B slot (mod 3)
  for (int t = 0; t < NT; ++t) {
    const char* Bb = smem + bc * 16384;
    v4i bfr[NSEG];
    v4i a[4];

    // A direct loads for tile t (4 VMEM, oldest in queue after drain)
    const signed char* aT = wA + t * 64;
    a[0] = LD16(aT + 0 * AROW);
    a[1] = LD16(aT + 1 * AROW);
    a[2] = LD16(aT + 2 * AROW);
    a[3] = LD16(aT + 3 * AROW);
    FENCE;
    // B stage 2 ahead into the dead 3rd slot (2 VMEM, newest)
    if (t + 2 < NT) { STAGE_B(t + 2, 0, bs); STAGE_B(t + 2, 1, bs); }
    FENCE;

    // B fragments for tile t (4 ds_reads, zero-conflict)
    bfr[0] = LD16(Bb + 0 * 4096 + wn * 1024 + aSw);
    bfr[1] = LD16(Bb + 1 * 4096 + wn * 1024 + aSw);
    bfr[2] = LD16(Bb + 2 * 4096 + wn * 1024 + aSw);
    bfr[3] = LD16(Bb + 3 * 4096 + wn * 1024 + aSw);

    // compiler inserts vmcnt(2) before first a[] use: a[] done, B(t+1) done,
    // B(t+2) still flying.
    WAITL(3);  MM4(0);
    WAITL(2);  MM4(1);
    WAITL(1);  MM4(2);
    WAITL(0);  MM4(3);

    __builtin_amdgcn_s_barrier();   // B(t+1) proven landed; slot rotate safe

    bc = (bc == 2) ? 0 : bc + 1;
    bs = (bs == 2) ? 0 : bs + 1;
  }
  asm volatile("s_waitcnt lgkmcnt(0) vmcnt(0)" ::: "memory");

  // ---------------- epilogue ----------------
  // C/D layout: col = lane&15 (d), row = (lane>>4)*4 + reg (dtype-independent)
  const int d = n0 + wn * 16 + l15;
  float bsv[NSEG], thv[NSEG], swv[NSEG];
#pragma unroll
  for (int s = 0; s < NSEG; ++s) {
    bsv[s] = b_seg[s * N_DIM + d];
    thv[s] = thr[s * N_DIM + d];
    swv[s] = sw[s * N_DIM + d];
  }
#pragma unroll
  for (int f = 0; f < 4; ++f) {
#pragma unroll
    for (int r = 0; r < 4; ++r) {
      const int brow = m0 + wm * 64 + f * 16 + kg * 4 + r;
      const float sxr = sx[brow];
      const float4 g = *(const float4*)(gates + (size_t)brow * 4);
      const float gv[NSEG] = {g.x, g.y, g.z, g.w};
      float sum = 0.f, prod = 1.f;
#pragma unroll
      for (int s = 0; s < NSEG; ++s) {
        const float seg = (float)acc[s][f][r] * (sxr * swv[s]) + bsv[s];
        const float pl = 1.f / (1.f + __expf(-5.f * (seg - thv[s])));
        const float st = seg * pl * gv[s];
        sum += st;
        prod *= st;
      }
      const float gm = sqrtf(sqrtf(fabsf(prod)));   // |prod|^(1/4)
      out[(size_t)brow * N_DIM + d] = sum + 0.1f * (prod < 0.f ? -gm : gm);
    }
  }
#undef STAGE_B
#undef MFMAI
#undef LD16
#undef WAITL
#undef FENCE
#undef MM4
#undef AROW
}

extern "C" void kernel_launch(void* const* d_in, const int* in_sizes, int n_in,
                              void* d_out, int out_size, void* d_ws, size_t ws_size,
                              hipStream_t stream) {
  const float* x      = (const float*)d_in[0];
  const float* W_seg  = (const float*)d_in[1];
  const float* b_seg  = (const float*)d_in[2];
  const float* thr    = (const float*)d_in[3];
  const float* W_gate = (const float*)d_in[4];
  const float* b_gate = (const float*)d_in[5];
  float* out = (float*)d_out;

  // workspace: xq 16MB | wq 32MB | sx 32KB | sw 32KB | gates 128KB
  signed char* xq = (signed char*)d_ws;
  signed char* wq = xq + (size_t)B_DIM * K_DIM;
  float* sx = (float*)(wq + (size_t)NSEG * N_DIM * K_DIM);
  float* sw = sx + B_DIM;
  float* gates = sw + NSEG * N_DIM;

  xquant_gates_kernel<<<B_DIM, 256, 0, stream>>>(x, W_gate, b_gate, xq, sx, gates);
  wquant_kernel<<<NSEG * N_DIM, 256, 0, stream>>>(W_seg, wq, sw);

  seg_gemm_kernel<<<2048, 512, 0, stream>>>(xq, wq, sx, sw, b_seg, thr, gates, out);
}

// Round 17
// 219.236 us; speedup vs baseline: 1.5010x; 1.5010x over previous
//
#include <hip/hip_runtime.h>
#include <stdint.h>

#define B_DIM 8192
#define K_DIM 2048
#define N_DIM 2048
#define NSEG 4
#define NT (K_DIM / 64)   // 32 K-tiles of BK=64

typedef int v4i __attribute__((ext_vector_type(4)));

typedef const __attribute__((address_space(1))) void* gas_ptr;
typedef __attribute__((address_space(3))) void* lds_ptr;

// ---- fused: x row quantize (per-row int8) + gates = sigmoid(x@Wg^T+bg) ----
__global__ __launch_bounds__(256)
void xquant_gates_kernel(const float* __restrict__ x, const float* __restrict__ Wg,
                         const float* __restrict__ bg, signed char* __restrict__ xq,
                         float* __restrict__ sx, float* __restrict__ gates) {
  const int b = blockIdx.x;
  const int tid = threadIdx.x;
  const size_t base = (size_t)b * K_DIM + tid * 8;
  const float4 v0 = *(const float4*)(x + base);
  const float4 v1 = *(const float4*)(x + base + 4);

  float a[4];
#pragma unroll
  for (int s = 0; s < 4; ++s) {
    const float4 w0 = *(const float4*)(Wg + (size_t)s * K_DIM + tid * 8);
    const float4 w1 = *(const float4*)(Wg + (size_t)s * K_DIM + tid * 8 + 4);
    a[s] = v0.x * w0.x + v0.y * w0.y + v0.z * w0.z + v0.w * w0.w
         + v1.x * w1.x + v1.y * w1.y + v1.z * w1.z + v1.w * w1.w;
  }
  float m = fmaxf(fmaxf(fmaxf(fabsf(v0.x), fabsf(v0.y)), fmaxf(fabsf(v0.z), fabsf(v0.w))),
                  fmaxf(fmaxf(fabsf(v1.x), fabsf(v1.y)), fmaxf(fabsf(v1.z), fabsf(v1.w))));
#pragma unroll
  for (int off = 1; off < 64; off <<= 1) {
    m = fmaxf(m, __shfl_xor(m, off));
#pragma unroll
    for (int s = 0; s < 4; ++s) a[s] += __shfl_xor(a[s], off);
  }
  __shared__ float redg[4][4];
  __shared__ float rmx[4];
  const int wv = tid >> 6;
  if ((tid & 63) == 0) {
    rmx[wv] = m;
#pragma unroll
    for (int s = 0; s < 4; ++s) redg[wv][s] = a[s];
  }
  __syncthreads();
  const float rm = fmaxf(fmaxf(rmx[0], rmx[1]), fmaxf(rmx[2], rmx[3]));
  const float inv = 127.0f / fmaxf(rm, 1e-30f);
  const int q0 = __float2int_rn(v0.x * inv), q1 = __float2int_rn(v0.y * inv);
  const int q2 = __float2int_rn(v0.z * inv), q3 = __float2int_rn(v0.w * inv);
  const int q4 = __float2int_rn(v1.x * inv), q5 = __float2int_rn(v1.y * inv);
  const int q6 = __float2int_rn(v1.z * inv), q7 = __float2int_rn(v1.w * inv);
  const int lo = (q0 & 255) | ((q1 & 255) << 8) | ((q2 & 255) << 16) | ((q3 & 255) << 24);
  const int hi = (q4 & 255) | ((q5 & 255) << 8) | ((q6 & 255) << 16) | ((q7 & 255) << 24);
  ((int2*)xq)[(size_t)b * 256 + tid] = make_int2(lo, hi);
  if (tid == 0) sx[b] = rm * (1.0f / 127.0f);
  if (tid < 4) {
    float v = redg[0][tid] + redg[1][tid] + redg[2][tid] + redg[3][tid] + bg[tid];
    gates[(size_t)b * 4 + tid] = 1.f / (1.f + __expf(-v));
  }
}

// ---- W row quantize: one block per (seg,d) row of 2048 ----
__global__ __launch_bounds__(256)
void wquant_kernel(const float* __restrict__ W, signed char* __restrict__ wq,
                   float* __restrict__ sw) {
  const int row = blockIdx.x;           // s*N_DIM + d
  const int tid = threadIdx.x;
  const size_t base = (size_t)row * K_DIM + tid * 8;
  const float4 v0 = *(const float4*)(W + base);
  const float4 v1 = *(const float4*)(W + base + 4);
  float m = fmaxf(fmaxf(fmaxf(fabsf(v0.x), fabsf(v0.y)), fmaxf(fabsf(v0.z), fabsf(v0.w))),
                  fmaxf(fmaxf(fabsf(v1.x), fabsf(v1.y)), fmaxf(fabsf(v1.z), fabsf(v1.w))));
#pragma unroll
  for (int off = 1; off < 64; off <<= 1) m = fmaxf(m, __shfl_xor(m, off));
  __shared__ float rmx[4];
  if ((tid & 63) == 0) rmx[tid >> 6] = m;
  __syncthreads();
  const float rm = fmaxf(fmaxf(rmx[0], rmx[1]), fmaxf(rmx[2], rmx[3]));
  const float inv = 127.0f / fmaxf(rm, 1e-30f);
  const int q0 = __float2int_rn(v0.x * inv), q1 = __float2int_rn(v0.y * inv);
  const int q2 = __float2int_rn(v0.z * inv), q3 = __float2int_rn(v0.w * inv);
  const int q4 = __float2int_rn(v1.x * inv), q5 = __float2int_rn(v1.y * inv);
  const int q6 = __float2int_rn(v1.z * inv), q7 = __float2int_rn(v1.w * inv);
  const int lo = (q0 & 255) | ((q1 & 255) << 8) | ((q2 & 255) << 16) | ((q3 & 255) << 24);
  const int hi = (q4 & 255) | ((q5 & 255) << 8) | ((q6 & 255) << 16) | ((q7 & 255) << 24);
  ((int2*)wq)[(size_t)row * 256 + tid] = make_int2(lo, hi);
  if (tid == 0) sw[row] = rm * (1.0f / 127.0f);
}

// ------- fused 4-seg GEMM, i8 16x16x64: R12 schedule + L2-local mapping -----
// FINAL (= R14, the verified best: 184.5us GEMM / 219us total).
// Block 128 r x 64 d x 4 segs; 8 waves 2Mx4N; per-wave 64 r x 16 d x 4 segs;
// acc v4i[4][4]; A dbuf 2x8K + B tri-ring 3x16K = 64 KB; 2 blocks/CU.
// XCD-local 2D window mapping: XCD x gets an 8 m0 x 8 n0 concurrent window
// (A panel 2MB L2-resident; B window 4MB, 8-way reuse) -> FETCH 474->112 MB.
// Failure matrix that pins this design (R15/R16): removing either operand
// from LDS regresses ~1.8x (B-direct: spill + uncoalesced; A-direct: per-tile
// global latency exposed); schedule variants and occupancy changes are flat.
__global__ __launch_bounds__(512, 4)
void seg_gemm_kernel(const signed char* __restrict__ Xq,
                     const signed char* __restrict__ Wq,
                     const float* __restrict__ sx,
                     const float* __restrict__ sw,
                     const float* __restrict__ b_seg,
                     const float* __restrict__ thr,
                     const float* __restrict__ gates,
                     float* __restrict__ out) {
  __shared__ __align__(128) char smem[65536];   // A 16K | B 48K

  const int tid = threadIdx.x;
  const int lane = tid & 63;
  const int wid = tid >> 6;
  const int wm = wid >> 2;        // 0..1 (m half: 64 rows)
  const int wn = wid & 3;         // 0..3 (d quarter)

  // ---- XCD-local 2D window mapping (bijective) ----
  const int id = blockIdx.x;
  const int x = id & 7;
  const int c = id >> 3;
  const int mIdx = (c >> 3) & 7;
  const int nIdx = (c & 7) | ((c >> 6) << 3);
  const int m0 = (x * 8 + mIdx) * 128;
  const int n0 = nIdx * 64;

  // ---- staging constants (verified zero-conflict, R10-R14) ----
  const int row_st = tid >> 2;                       // 0..127
  const int kc    = (tid & 3) ^ ((tid >> 3) & 3);    // chunk swizzle (involution)
  const int keOff = kc * 16;
  const int ldsd  = tid * 16;                        // 0..8191

  // ---- read constants (verified zero-conflict, R10-R14) ----
  const int l15 = lane & 15;
  const int kg  = lane >> 4;       // 0..3
  const int aSw = l15 * 64 + ((kg ^ ((l15 >> 1) & 3)) << 4);

  v4i acc[NSEG][4];
#pragma unroll
  for (int s = 0; s < NSEG; ++s)
#pragma unroll
    for (int f = 0; f < 4; ++f) acc[s][f] = (v4i){0, 0, 0, 0};

#define STAGE_A(t_) do {                                                            \
    const signed char* s0_ = Xq + (size_t)(m0 + row_st) * K_DIM + (t_) * 64 + keOff; \
    __builtin_amdgcn_global_load_lds((gas_ptr)s0_, (lds_ptr)(smem + ((t_) & 1) * 8192 + ldsd), 16, 0, 0); \
  } while (0)

#define STAGE_B(t_, h_, bb_) do {                                                   \
    const signed char* s0_ = Wq + ((size_t)((h_) * 2 + (tid >> 8)) * N_DIM + (n0 + ((tid >> 2) & 63))) * K_DIM + (t_) * 64 + keOff; \
    __builtin_amdgcn_global_load_lds((gas_ptr)s0_, (lds_ptr)(smem + 16384 + (bb_) * 16384 + (h_) * 8192 + ldsd), 16, 0, 0); \
  } while (0)

#define MFMAI(a_, b_, c_) __builtin_amdgcn_mfma_i32_16x16x64_i8(a_, b_, c_, 0, 0, 0)
#define LD16(p_) (*(const v4i*)(p_))
#define WAITL(n_) asm volatile("s_waitcnt lgkmcnt(" #n_ ")" ::: "memory")

#define MM4(f_) do {                                                                \
    __builtin_amdgcn_s_setprio(1);                                                  \
    acc[0][(f_)] = MFMAI(a[(f_)], bfr[0], acc[0][(f_)]);                            \
    acc[1][(f_)] = MFMAI(a[(f_)], bfr[1], acc[1][(f_)]);                            \
    acc[2][(f_)] = MFMAI(a[(f_)], bfr[2], acc[2][(f_)]);                            \
    acc[3][(f_)] = MFMAI(a[(f_)], bfr[3], acc[3][(f_)]);                            \
    __builtin_amdgcn_s_setprio(0);                                                  \
  } while (0)

  // ---- prologue: A(0), B(0)->buf0, B(1)->buf1 (5 instr); keep B(1) flying --
  STAGE_A(0);
  STAGE_B(0, 0, 0); STAGE_B(0, 1, 0);
  STAGE_B(1, 0, 1); STAGE_B(1, 1, 1);
  asm volatile("s_waitcnt vmcnt(2)" ::: "memory");   // A(0),B(0) landed
  __builtin_amdgcn_s_barrier();

  int bc = 0, bs = 2;   // current / stage-target B buffer (mod 3)
  for (int t = 0; t < NT; ++t) {
    const char* Ab = smem + (t & 1) * 8192 + wm * 4096;
    const char* Bb = smem + 16384 + bc * 16384;
    v4i bfr[NSEG];
    v4i a[4];

    // ---- burst: 4 B + 4 A ds_reads, then A(t+1) stage (VMEM) ----
    bfr[0] = LD16(Bb + 0 * 4096 + wn * 1024 + aSw);
    bfr[1] = LD16(Bb + 1 * 4096 + wn * 1024 + aSw);
    bfr[2] = LD16(Bb + 2 * 4096 + wn * 1024 + aSw);
    bfr[3] = LD16(Bb + 3 * 4096 + wn * 1024 + aSw);
    a[0] = LD16(Ab + 0 * 1024 + aSw);
    a[1] = LD16(Ab + 1 * 1024 + aSw);
    a[2] = LD16(Ab + 2 * 1024 + aSw);
    a[3] = LD16(Ab + 3 * 1024 + aSw);
    if (t + 1 < NT) STAGE_A(t + 1);

    WAITL(3);  MM4(0);                               // b0-3 + a0 done
    WAITL(2);
    if (t + 2 < NT) STAGE_B(t + 2, 0, bs);
    MM4(1);
    WAITL(1);
    if (t + 2 < NT) STAGE_B(t + 2, 1, bs);
    MM4(2);
    WAITL(0);  MM4(3);

    if (t < NT - 2)      { asm volatile("s_waitcnt vmcnt(2)" ::: "memory"); }
    else if (t == NT - 2){ asm volatile("s_waitcnt vmcnt(0)" ::: "memory"); }
    __builtin_amdgcn_s_barrier();

    bc = (bc == 2) ? 0 : bc + 1;
    bs = (bs == 2) ? 0 : bs + 1;
  }
  asm volatile("s_waitcnt lgkmcnt(0) vmcnt(0)" ::: "memory");

  // ---------------- epilogue ----------------
  // C/D layout: col = lane&15 (d), row = (lane>>4)*4 + reg (dtype-independent)
  const int d = n0 + wn * 16 + l15;
  float bsv[NSEG], thv[NSEG], swv[NSEG];
#pragma unroll
  for (int s = 0; s < NSEG; ++s) {
    bsv[s] = b_seg[s * N_DIM + d];
    thv[s] = thr[s * N_DIM + d];
    swv[s] = sw[s * N_DIM + d];
  }
#pragma unroll
  for (int f = 0; f < 4; ++f) {
#pragma unroll
    for (int r = 0; r < 4; ++r) {
      const int brow = m0 + wm * 64 + f * 16 + kg * 4 + r;
      const float sxr = sx[brow];
      const float4 g = *(const float4*)(gates + (size_t)brow * 4);
      const float gv[NSEG] = {g.x, g.y, g.z, g.w};
      float sum = 0.f, prod = 1.f;
#pragma unroll
      for (int s = 0; s < NSEG; ++s) {
        const float seg = (float)acc[s][f][r] * (sxr * swv[s]) + bsv[s];
        const float pl = 1.f / (1.f + __expf(-5.f * (seg - thv[s])));
        const float st = seg * pl * gv[s];
        sum += st;
        prod *= st;
      }
      const float gm = sqrtf(sqrtf(fabsf(prod)));   // |prod|^(1/4)
      out[(size_t)brow * N_DIM + d] = sum + 0.1f * (prod < 0.f ? -gm : gm);
    }
  }
#undef STAGE_A
#undef STAGE_B
#undef MFMAI
#undef LD16
#undef WAITL
#undef MM4
}

extern "C" void kernel_launch(void* const* d_in, const int* in_sizes, int n_in,
                              void* d_out, int out_size, void* d_ws, size_t ws_size,
                              hipStream_t stream) {
  const float* x      = (const float*)d_in[0];
  const float* W_seg  = (const float*)d_in[1];
  const float* b_seg  = (const float*)d_in[2];
  const float* thr    = (const float*)d_in[3];
  const float* W_gate = (const float*)d_in[4];
  const float* b_gate = (const float*)d_in[5];
  float* out = (float*)d_out;

  // workspace: xq 16MB | wq 32MB | sx 32KB | sw 32KB | gates 128KB
  signed char* xq = (signed char*)d_ws;
  signed char* wq = xq + (size_t)B_DIM * K_DIM;
  float* sx = (float*)(wq + (size_t)NSEG * N_DIM * K_DIM);
  float* sw = sx + B_DIM;
  float* gates = sw + NSEG * N_DIM;

  xquant_gates_kernel<<<B_DIM, 256, 0, stream>>>(x, W_gate, b_gate, xq, sx, gates);
  wquant_kernel<<<NSEG * N_DIM, 256, 0, stream>>>(W_seg, wq, sw);

  seg_gemm_kernel<<<2048, 512, 0, stream>>>(xq, wq, sx, sw, b_seg, thr, gates, out);
}